// Round 1
// baseline (856.430 us; speedup 1.0000x reference)
//
#include <hip/hip_runtime.h>

#define NB 2048
#define NT 512

// broadcast lane j's value of v to all lanes (wave-uniform j -> v_readlane)
__device__ __forceinline__ float rl(float v, int j) {
    return __int_as_float(__builtin_amdgcn_readlane(__float_as_int(v), j));
}

// tanh(x) = 1 - 2/(exp(2x)+1); clamp to avoid inf/inf NaN, exp via v_exp_f32
__device__ __forceinline__ float fast_tanh(float z) {
    z = fminf(fmaxf(z, -15.f), 15.f);
    const float e = __expf(2.f * z);
    return 1.f - __fdividef(2.f, e + 1.f);
}

// lane = hidden index i (H=64 == wave width), wave = batch element.
// Weight rows W[i][:] live in VGPRs (3*64 = 192 regs); h[j] broadcast by readlane.
extern "C" __global__ void __launch_bounds__(256, 2)
rnn2_fp32(const float* __restrict__ x,      // [B, T, 1]
          const float* __restrict__ W_ih0,  // [64, 1]
          const float* __restrict__ W_hh0,  // [64, 64]
          const float* __restrict__ b_ih0,  // [64]
          const float* __restrict__ b_hh0,  // [64]
          const float* __restrict__ W_ih1,  // [64, 64]
          const float* __restrict__ W_hh1,  // [64, 64]
          const float* __restrict__ b_ih1,  // [64]
          const float* __restrict__ b_hh1,  // [64]
          const float* __restrict__ W_fc,   // [1, 64]
          const float* __restrict__ b_fc,   // [1]
          float* __restrict__ out)          // [B, 1]
{
    const int lane = threadIdx.x & 63;
    const int wv = (int)((blockIdx.x * blockDim.x + threadIdx.x) >> 6);
    const int b = __builtin_amdgcn_readfirstlane(wv);  // batch index, wave-uniform

    // ---- persistent per-lane weight rows in VGPRs ----
    float w0[64], wi1[64], w1[64];
    {
        const float4* p0 = (const float4*)(W_hh0 + lane * 64);
        const float4* p1 = (const float4*)(W_ih1 + lane * 64);
        const float4* p2 = (const float4*)(W_hh1 + lane * 64);
#pragma unroll
        for (int q = 0; q < 16; ++q) {
            float4 a = p0[q]; w0 [4*q] = a.x; w0 [4*q+1] = a.y; w0 [4*q+2] = a.z; w0 [4*q+3] = a.w;
            float4 c = p1[q]; wi1[4*q] = c.x; wi1[4*q+1] = c.y; wi1[4*q+2] = c.z; wi1[4*q+3] = c.w;
            float4 d = p2[q]; w1 [4*q] = d.x; w1 [4*q+1] = d.y; w1 [4*q+2] = d.z; w1 [4*q+3] = d.w;
        }
    }
    const float wih0 = W_ih0[lane];
    const float c0 = b_ih0[lane] + b_hh0[lane];  // combined biases, layer 0
    const float c1 = b_ih1[lane] + b_hh1[lane];  // combined biases, layer 1

    float h0 = 0.f, h1 = 0.f;
    const float* xb = x + (long)b * NT;

    for (int t = 0; t < NT; ++t) {
        const float xv = xb[t];  // wave-uniform -> s_load
        // layer-0 preactivation starts at x*W_ih0 + biases
        float a0  = __fmaf_rn(xv, wih0, c0);
        float a0b = 0.f;
        // layer-1 h-recurrence (uses h1_old, independent of layer 0 -> interleave)
        float a1 = c1, a1b = 0.f;
#pragma unroll
        for (int j = 0; j < 64; j += 2) {
            const float h00 = rl(h0, j);
            const float h01 = rl(h0, j + 1);
            const float h10 = rl(h1, j);
            const float h11 = rl(h1, j + 1);
            a0  = __fmaf_rn(w0[j],     h00, a0);
            a1  = __fmaf_rn(w1[j],     h10, a1);
            a0b = __fmaf_rn(w0[j + 1], h01, a0b);
            a1b = __fmaf_rn(w1[j + 1], h11, a1b);
        }
        const float h0n = fast_tanh(a0 + a0b);

        // layer-1 input projection with fresh h0n
        float s1 = 0.f, s1b = 0.f;
#pragma unroll
        for (int j = 0; j < 64; j += 2) {
            const float g0 = rl(h0n, j);
            const float g1 = rl(h0n, j + 1);
            s1  = __fmaf_rn(wi1[j],     g0, s1);
            s1b = __fmaf_rn(wi1[j + 1], g1, s1b);
        }
        h1 = fast_tanh(a1 + a1b + s1 + s1b);
        h0 = h0n;
    }

    // FC epilogue: out[b] = sum_i h1[i] * W_fc[0][i] + b_fc
    float p = h1 * W_fc[lane];
#pragma unroll
    for (int off = 32; off > 0; off >>= 1)
        p += __shfl_xor(p, off, 64);
    if (lane == 0) out[b] = p + b_fc[0];
}

extern "C" void kernel_launch(void* const* d_in, const int* in_sizes, int n_in,
                              void* d_out, int out_size, void* d_ws, size_t ws_size,
                              hipStream_t stream) {
    const float* x     = (const float*)d_in[0];
    const float* W_ih0 = (const float*)d_in[1];
    const float* W_hh0 = (const float*)d_in[2];
    const float* b_ih0 = (const float*)d_in[3];
    const float* b_hh0 = (const float*)d_in[4];
    const float* W_ih1 = (const float*)d_in[5];
    const float* W_hh1 = (const float*)d_in[6];
    const float* b_ih1 = (const float*)d_in[7];
    const float* b_hh1 = (const float*)d_in[8];
    const float* W_fc  = (const float*)d_in[9];
    const float* b_fc  = (const float*)d_in[10];
    float* out = (float*)d_out;

    // 2048 batch elements, 1 wave each; 256-thread blocks = 4 waves/block
    rnn2_fp32<<<NB / 4, 256, 0, stream>>>(x, W_ih0, W_hh0, b_ih0, b_hh0,
                                          W_ih1, W_hh1, b_ih1, b_hh1,
                                          W_fc, b_fc, out);
}

// Round 2
// 515.798 us; speedup vs baseline: 1.6604x; 1.6604x over previous
//
#include <hip/hip_runtime.h>

#define TT 512
#define RS 72  // LDS plane row stride in bf16 elems (64 + 8 pad, keeps 16B align)

typedef __attribute__((ext_vector_type(8))) short short8;
typedef __attribute__((ext_vector_type(4))) float floatx4;

__device__ __forceinline__ unsigned short f2bf(float f) {
    unsigned u = __float_as_uint(f);
    return (unsigned short)((u + 0x7FFFu + ((u >> 16) & 1u)) >> 16);  // RTNE
}
__device__ __forceinline__ float bf2f(unsigned short b) {
    return __uint_as_float(((unsigned)b) << 16);
}
__device__ __forceinline__ float fast_tanh(float z) {
    z = fminf(fmaxf(z, -15.f), 15.f);
    const float e = __expf(2.f * z);
    return 1.f - __fdividef(2.f, e + 1.f);
}

// Transposed-form MFMA RNN: D[hidden(M=64) x batch(N=16)] per block.
// Wave w owns hidden rows [16w,16w+16). A-operand = weight rows (static VGPR
// bf16 hi/lo frags), B-operand = h read from LDS planes [batch][hidden] bf16.
// Split-3 products (Whi*hhi + Whi*hlo + Wlo*hhi) ~= fp32 precision.
__global__ void __launch_bounds__(256, 1)
rnn2_mfma(const float* __restrict__ x,
          const float* __restrict__ W_ih0, const float* __restrict__ W_hh0,
          const float* __restrict__ b_ih0, const float* __restrict__ b_hh0,
          const float* __restrict__ W_ih1, const float* __restrict__ W_hh1,
          const float* __restrict__ b_ih1, const float* __restrict__ b_hh1,
          const float* __restrict__ W_fc, const float* __restrict__ b_fc,
          float* __restrict__ out)
{
    __shared__ short h0hA[16][RS], h0lA[16][RS];  // h0n double buffer A
    __shared__ short h0hB[16][RS], h0lB[16][RS];  // h0n double buffer B
    __shared__ short h1h[16][RS], h1l[16][RS];    // h1 (single buffer)
    __shared__ float xt[16][TT + 1];
    __shared__ float red[4][16];

    const int tid = threadIdx.x;
    const int lane = tid & 63;
    const int w = tid >> 6;
    const int n = lane & 15;   // batch col within tile
    const int q = lane >> 4;   // quad
    const int b0 = blockIdx.x * 16;

    // zero h planes (h(-1) = 0)
    {
        short* pl[6] = {&h0hA[0][0], &h0lA[0][0], &h0hB[0][0],
                        &h0lB[0][0], &h1h[0][0], &h1l[0][0]};
#pragma unroll
        for (int a = 0; a < 6; ++a)
            for (int i = tid; i < 16 * RS; i += 256) pl[a][i] = 0;
    }
    // stage x tile [16][512] into LDS (pad 1 float -> conflict-free reads)
    for (int i = tid; i < 16 * (TT / 4); i += 256) {
        const int r = i >> 7, c4 = (i & 127) << 2;
        float4 v = *(const float4*)(x + (long)(b0 + r) * TT + c4);
        xt[r][c4] = v.x; xt[r][c4 + 1] = v.y; xt[r][c4 + 2] = v.z; xt[r][c4 + 3] = v.w;
    }

    // ---- static weight fragments (A-operand) ----
    const int mrow = 16 * w + n;      // A row (hidden-out) this lane holds
    const int m4 = 16 * w + 4 * q;    // first D row this lane holds
    short8 w0h[2], w0l[2], w1h[4], w1l[4];
    auto mkfrag = [&](const float* p, short8& hi, short8& lo) {
#pragma unroll
        for (int j = 0; j < 8; ++j) {
            const float v = p[j];
            const unsigned short h = f2bf(v);
            hi[j] = (short)h;
            lo[j] = (short)f2bf(v - bf2f(h));
        }
    };
#pragma unroll
    for (int s = 0; s < 2; ++s) {
        mkfrag(W_hh0 + mrow * 64 + 32 * s + 8 * q, w0h[s], w0l[s]);
        mkfrag(W_ih1 + mrow * 64 + 32 * s + 8 * q, w1h[s], w1l[s]);        // K-steps 0,1
        mkfrag(W_hh1 + mrow * 64 + 32 * s + 8 * q, w1h[2 + s], w1l[2 + s]); // K-steps 2,3
    }
    const float4 wih0v = *(const float4*)(W_ih0 + m4);
    float4 bv0 = *(const float4*)(b_ih0 + m4);
    { float4 t2 = *(const float4*)(b_hh0 + m4); bv0.x += t2.x; bv0.y += t2.y; bv0.z += t2.z; bv0.w += t2.w; }
    float4 bv1 = *(const float4*)(b_ih1 + m4);
    { float4 t2 = *(const float4*)(b_hh1 + m4); bv1.x += t2.x; bv1.y += t2.y; bv1.z += t2.z; bv1.w += t2.w; }
    const float4 wfcv = *(const float4*)(W_fc + m4);

    __syncthreads();

    const floatx4 zero4 = {0.f, 0.f, 0.f, 0.f};
    float4 hv1 = {0.f, 0.f, 0.f, 0.f};

    for (int t = 0; t < TT; ++t) {
        // read buffer (h0n(t-1)) alternates; t=0 reads zeroed A
        const short (*rh)[RS] = (t & 1) ? h0hB : h0hA;
        const short (*rl)[RS] = (t & 1) ? h0lB : h0lA;
        short (*wh)[RS] = (t & 1) ? h0hA : h0hB;
        short (*wl)[RS] = (t & 1) ? h0lA : h0lB;

        // --- S1: B-frag reads ---
        short8 bh[2], bl[2], ch[2], cl[2];
#pragma unroll
        for (int s = 0; s < 2; ++s) {
            bh[s] = *(const short8*)&rh[n][32 * s + 8 * q];
            bl[s] = *(const short8*)&rl[n][32 * s + 8 * q];
            ch[s] = *(const short8*)&h1h[n][32 * s + 8 * q];
            cl[s] = *(const short8*)&h1l[n][32 * s + 8 * q];
        }
        const float xv = xt[n][t];

        floatx4 aA0 = zero4, aB0 = zero4, aA1 = zero4, aB1 = zero4;
#pragma unroll
        for (int s = 0; s < 2; ++s) {
            aA0 = __builtin_amdgcn_mfma_f32_16x16x32_bf16(w0h[s], bh[s], aA0, 0, 0, 0);
            aA1 = __builtin_amdgcn_mfma_f32_16x16x32_bf16(w1h[2 + s], ch[s], aA1, 0, 0, 0);
            aB0 = __builtin_amdgcn_mfma_f32_16x16x32_bf16(w0h[s], bl[s], aB0, 0, 0, 0);
            aB1 = __builtin_amdgcn_mfma_f32_16x16x32_bf16(w1h[2 + s], cl[s], aB1, 0, 0, 0);
            aB0 = __builtin_amdgcn_mfma_f32_16x16x32_bf16(w0l[s], bh[s], aB0, 0, 0, 0);
            aB1 = __builtin_amdgcn_mfma_f32_16x16x32_bf16(w1l[2 + s], ch[s], aB1, 0, 0, 0);
        }

        // --- layer-0 epilogue: +x*Wih0 + bias, tanh, split, write h0n planes ---
        unsigned short hh[4], hl[4];
#pragma unroll
        for (int r = 0; r < 4; ++r) {
            const float wr = (r == 0) ? wih0v.x : (r == 1) ? wih0v.y : (r == 2) ? wih0v.z : wih0v.w;
            const float br = (r == 0) ? bv0.x : (r == 1) ? bv0.y : (r == 2) ? bv0.z : bv0.w;
            const float pre = aA0[r] + aB0[r] + xv * wr + br;
            const float h = fast_tanh(pre);
            hh[r] = f2bf(h);
            hl[r] = f2bf(h - bf2f(hh[r]));
        }
        *(uint2*)&wh[n][m4] = make_uint2((unsigned)hh[0] | ((unsigned)hh[1] << 16),
                                         (unsigned)hh[2] | ((unsigned)hh[3] << 16));
        *(uint2*)&wl[n][m4] = make_uint2((unsigned)hl[0] | ((unsigned)hl[1] << 16),
                                         (unsigned)hl[2] | ((unsigned)hl[3] << 16));
        __syncthreads();  // h0n(t) ready; h1(t-1) reads all done

        // --- S2: layer-1 input projection with fresh h0n(t) ---
#pragma unroll
        for (int s = 0; s < 2; ++s) {
            const short8 nh = *(const short8*)&wh[n][32 * s + 8 * q];
            const short8 nl = *(const short8*)&wl[n][32 * s + 8 * q];
            aA1 = __builtin_amdgcn_mfma_f32_16x16x32_bf16(w1h[s], nh, aA1, 0, 0, 0);
            aB1 = __builtin_amdgcn_mfma_f32_16x16x32_bf16(w1h[s], nl, aB1, 0, 0, 0);
            aB1 = __builtin_amdgcn_mfma_f32_16x16x32_bf16(w1l[s], nh, aB1, 0, 0, 0);
        }
#pragma unroll
        for (int r = 0; r < 4; ++r) {
            const float br = (r == 0) ? bv1.x : (r == 1) ? bv1.y : (r == 2) ? bv1.z : bv1.w;
            const float pre = aA1[r] + aB1[r] + br;
            const float h = fast_tanh(pre);
            if (r == 0) hv1.x = h; else if (r == 1) hv1.y = h; else if (r == 2) hv1.z = h; else hv1.w = h;
            hh[r] = f2bf(h);
            hl[r] = f2bf(h - bf2f(hh[r]));
        }
        *(uint2*)&h1h[n][m4] = make_uint2((unsigned)hh[0] | ((unsigned)hh[1] << 16),
                                          (unsigned)hh[2] | ((unsigned)hh[3] << 16));
        *(uint2*)&h1l[n][m4] = make_uint2((unsigned)hl[0] | ((unsigned)hl[1] << 16),
                                          (unsigned)hl[2] | ((unsigned)hl[3] << 16));
        __syncthreads();  // h1(t) ready for next step
    }

    // ---- FC epilogue: out[b] = sum_i h1[i]*W_fc[i] + b_fc ----
    float p = hv1.x * wfcv.x + hv1.y * wfcv.y + hv1.z * wfcv.z + hv1.w * wfcv.w;
    p += __shfl_xor(p, 16, 64);
    p += __shfl_xor(p, 32, 64);
    if (lane < 16) red[w][lane] = p;
    __syncthreads();
    if (w == 0 && lane < 16)
        out[b0 + lane] = red[0][lane] + red[1][lane] + red[2][lane] + red[3][lane] + b_fc[0];
}

extern "C" void kernel_launch(void* const* d_in, const int* in_sizes, int n_in,
                              void* d_out, int out_size, void* d_ws, size_t ws_size,
                              hipStream_t stream) {
    const float* x     = (const float*)d_in[0];
    const float* W_ih0 = (const float*)d_in[1];
    const float* W_hh0 = (const float*)d_in[2];
    const float* b_ih0 = (const float*)d_in[3];
    const float* b_hh0 = (const float*)d_in[4];
    const float* W_ih1 = (const float*)d_in[5];
    const float* W_hh1 = (const float*)d_in[6];
    const float* b_ih1 = (const float*)d_in[7];
    const float* b_hh1 = (const float*)d_in[8];
    const float* W_fc  = (const float*)d_in[9];
    const float* b_fc  = (const float*)d_in[10];
    float* out = (float*)d_out;

    rnn2_mfma<<<128, 256, 0, stream>>>(x, W_ih0, W_hh0, b_ih0, b_hh0,
                                       W_ih1, W_hh1, b_ih1, b_hh1,
                                       W_fc, b_fc, out);
}

// Round 3
// 435.000 us; speedup vs baseline: 1.9688x; 1.1857x over previous
//
#include <hip/hip_runtime.h>

#define TT 512

typedef __attribute__((ext_vector_type(8))) short short8;
typedef __attribute__((ext_vector_type(4))) float floatx4;

__device__ __forceinline__ unsigned short f2bf(float f) {
    unsigned u = __float_as_uint(f);
    return (unsigned short)((u + 0x7FFFu + ((u >> 16) & 1u)) >> 16);  // RTNE
}
__device__ __forceinline__ float bf2f(unsigned short b) {
    return __uint_as_float(((unsigned)b) << 16);
}
__device__ __forceinline__ float fast_tanh(float z) {
    z = fminf(fmaxf(z, -15.f), 15.f);
    const float e = __expf(2.f * z);
    return 1.f - __fdividef(2.f, e + 1.f);
}

// Layer-pipelined MFMA RNN, ONE barrier per superstep.
// Superstep s: h0(s) = tanh(W0·h0(s-1) + x(s)Wih0 + b0)   [L0]
//              h1(s-1) = tanh(Wi1·h0(s-1) + W1·h1(s-2) + b1) [L1]
// h planes in LDS, chunked layout [chunk][batch][8] -> conflict-free b128.
// Split-3 bf16 (Whi*hhi + Whi*hlo + Wlo*hhi) ~ fp32 precision.
__global__ void __launch_bounds__(256, 1)
rnn2_mfma(const float* __restrict__ x,
          const float* __restrict__ W_ih0, const float* __restrict__ W_hh0,
          const float* __restrict__ b_ih0, const float* __restrict__ b_hh0,
          const float* __restrict__ W_ih1, const float* __restrict__ W_hh1,
          const float* __restrict__ b_ih1, const float* __restrict__ b_hh1,
          const float* __restrict__ W_fc, const float* __restrict__ b_fc,
          float* __restrict__ out)
{
    // [buf][part hi/lo][chunk*128 + n*8] ; chunk c holds hidden k in [8c,8c+8)
    __shared__ short h0p[2][2][1024];
    __shared__ short h1p[2][2][1024];
    __shared__ float xt[16][TT + 1];
    __shared__ float red[4][16];

    const int tid = threadIdx.x;
    const int lane = tid & 63;
    const int w = tid >> 6;
    const int n = lane & 15;   // batch col / A-row within 16-tile
    const int q = lane >> 4;   // quad
    const int b0 = blockIdx.x * 16;

    // zero h planes (h0(-1), h1(-1), h1(-2) = 0)
    for (int i = tid; i < 2 * 2 * 1024; i += 256) {
        ((short*)h0p)[i] = 0;
        ((short*)h1p)[i] = 0;
    }
    // stage x tile [16][512]
    for (int i = tid; i < 16 * (TT / 4); i += 256) {
        const int r = i >> 7, c4 = (i & 127) << 2;
        float4 v = *(const float4*)(x + (long)(b0 + r) * TT + c4);
        xt[r][c4] = v.x; xt[r][c4 + 1] = v.y; xt[r][c4 + 2] = v.z; xt[r][c4 + 3] = v.w;
    }

    // ---- static weight fragments (A-operand), rows [16w,16w+16) ----
    const int mrow = 16 * w + n;   // A row this lane holds
    const int m4 = 16 * w + 4 * q; // first D row this lane holds
    short8 w0h[2], w0l[2], wi1h[2], wi1l[2], w1h[2], w1l[2];
    auto mkfrag = [&](const float* p, short8& hi, short8& lo) {
#pragma unroll
        for (int j = 0; j < 8; ++j) {
            const float v = p[j];
            const unsigned short h = f2bf(v);
            hi[j] = (short)h;
            lo[j] = (short)f2bf(v - bf2f(h));
        }
    };
#pragma unroll
    for (int s = 0; s < 2; ++s) {
        mkfrag(W_hh0 + mrow * 64 + 32 * s + 8 * q, w0h[s], w0l[s]);
        mkfrag(W_ih1 + mrow * 64 + 32 * s + 8 * q, wi1h[s], wi1l[s]);
        mkfrag(W_hh1 + mrow * 64 + 32 * s + 8 * q, w1h[s], w1l[s]);
    }
    const float4 wih0v = *(const float4*)(W_ih0 + m4);
    float4 bv0 = *(const float4*)(b_ih0 + m4);
    { float4 t2 = *(const float4*)(b_hh0 + m4); bv0.x += t2.x; bv0.y += t2.y; bv0.z += t2.z; bv0.w += t2.w; }
    float4 bv1 = *(const float4*)(b_ih1 + m4);
    { float4 t2 = *(const float4*)(b_hh1 + m4); bv1.x += t2.x; bv1.y += t2.y; bv1.z += t2.z; bv1.w += t2.w; }
    const float4 wfcv = *(const float4*)(W_fc + m4);

    // per-lane LDS offsets (shorts)
    const int rbase = 128 * q + 8 * n;                    // B-frag read, chunk s adds 512s
    const int wbase = (2 * w + (q >> 1)) * 128 + 8 * n + 4 * (q & 1);  // b64 write (rows m4..m4+3)

    __syncthreads();

    const floatx4 zero4 = {0.f, 0.f, 0.f, 0.f};

    // helpers
    auto bias_r = [] (const float4& v, int r) {
        return (r == 0) ? v.x : (r == 1) ? v.y : (r == 2) ? v.z : v.w;
    };
    auto pack4 = [] (const unsigned short* a) {
        return make_uint2((unsigned)a[0] | ((unsigned)a[1] << 16),
                          (unsigned)a[2] | ((unsigned)a[3] << 16));
    };

    // ---- pre-step s=0: h0(0) = tanh(x(0)*Wih0 + b0)  (W0·0 = 0) ----
    {
        const float xv = xt[n][0];
        unsigned short hh[4], hl[4];
#pragma unroll
        for (int r = 0; r < 4; ++r) {
            const float h = fast_tanh(xv * bias_r(wih0v, r) + bias_r(bv0, r));
            hh[r] = f2bf(h);
            hl[r] = f2bf(h - bf2f(hh[r]));
        }
        *(uint2*)&h0p[0][0][wbase] = pack4(hh);
        *(uint2*)&h0p[0][1][wbase] = pack4(hl);
    }
    __syncthreads();

    // ---- main loop: supersteps s = 1..511 ----
    for (int s = 1; s < TT; ++s) {
        const int rb0 = (s - 1) & 1;  // h0(s-1)
        const int wb0 = s & 1;        // h0(s)
        const int rb1 = s & 1;        // h1(s-2)
        const int wb1 = (s - 1) & 1;  // h1(s-1)

        short8 bh[2], bl[2], ch[2], cl[2];
#pragma unroll
        for (int k = 0; k < 2; ++k) {
            bh[k] = *(const short8*)&h0p[rb0][0][rbase + 512 * k];
            bl[k] = *(const short8*)&h0p[rb0][1][rbase + 512 * k];
            ch[k] = *(const short8*)&h1p[rb1][0][rbase + 512 * k];
            cl[k] = *(const short8*)&h1p[rb1][1][rbase + 512 * k];
        }
        const float xv = xt[n][s];

        floatx4 a0A = zero4, a0B = zero4, a0C = zero4;
        floatx4 a1A = zero4, a1B = zero4, a1C = zero4;
#pragma unroll
        for (int k = 0; k < 2; ++k) {
            a0A = __builtin_amdgcn_mfma_f32_16x16x32_bf16(w0h[k], bh[k], a0A, 0, 0, 0);
            a1A = __builtin_amdgcn_mfma_f32_16x16x32_bf16(wi1h[k], bh[k], a1A, 0, 0, 0);
            a0B = __builtin_amdgcn_mfma_f32_16x16x32_bf16(w0h[k], bl[k], a0B, 0, 0, 0);
            a1B = __builtin_amdgcn_mfma_f32_16x16x32_bf16(wi1h[k], bl[k], a1B, 0, 0, 0);
            a0C = __builtin_amdgcn_mfma_f32_16x16x32_bf16(w0l[k], bh[k], a0C, 0, 0, 0);
            a1C = __builtin_amdgcn_mfma_f32_16x16x32_bf16(wi1l[k], bh[k], a1C, 0, 0, 0);
        }
#pragma unroll
        for (int k = 0; k < 2; ++k) {
            a1A = __builtin_amdgcn_mfma_f32_16x16x32_bf16(w1h[k], ch[k], a1A, 0, 0, 0);
            a1B = __builtin_amdgcn_mfma_f32_16x16x32_bf16(w1h[k], cl[k], a1B, 0, 0, 0);
            a1C = __builtin_amdgcn_mfma_f32_16x16x32_bf16(w1l[k], ch[k], a1C, 0, 0, 0);
        }

        unsigned short hh[4], hl[4], gh[4], gl[4];
#pragma unroll
        for (int r = 0; r < 4; ++r) {
            const float p0 = a0A[r] + a0B[r] + a0C[r] + xv * bias_r(wih0v, r) + bias_r(bv0, r);
            const float h0n = fast_tanh(p0);
            hh[r] = f2bf(h0n);
            hl[r] = f2bf(h0n - bf2f(hh[r]));
            const float p1 = a1A[r] + a1B[r] + a1C[r] + bias_r(bv1, r);
            const float h1n = fast_tanh(p1);
            gh[r] = f2bf(h1n);
            gl[r] = f2bf(h1n - bf2f(gh[r]));
        }
        *(uint2*)&h0p[wb0][0][wbase] = pack4(hh);
        *(uint2*)&h0p[wb0][1][wbase] = pack4(hl);
        *(uint2*)&h1p[wb1][0][wbase] = pack4(gh);
        *(uint2*)&h1p[wb1][1][wbase] = pack4(gl);
        __syncthreads();
    }

    // ---- post-step s=512: h1(511) = tanh(Wi1·h0(511) + W1·h1(510) + b1) ----
    float p;
    {
        short8 bh[2], bl[2], ch[2], cl[2];
#pragma unroll
        for (int k = 0; k < 2; ++k) {
            bh[k] = *(const short8*)&h0p[1][0][rbase + 512 * k];  // h0(511), buf 511&1=1
            bl[k] = *(const short8*)&h0p[1][1][rbase + 512 * k];
            ch[k] = *(const short8*)&h1p[0][0][rbase + 512 * k];  // h1(510), buf 510&1=0
            cl[k] = *(const short8*)&h1p[0][1][rbase + 512 * k];
        }
        floatx4 a1A = zero4, a1B = zero4, a1C = zero4;
#pragma unroll
        for (int k = 0; k < 2; ++k) {
            a1A = __builtin_amdgcn_mfma_f32_16x16x32_bf16(wi1h[k], bh[k], a1A, 0, 0, 0);
            a1B = __builtin_amdgcn_mfma_f32_16x16x32_bf16(wi1h[k], bl[k], a1B, 0, 0, 0);
            a1C = __builtin_amdgcn_mfma_f32_16x16x32_bf16(wi1l[k], bh[k], a1C, 0, 0, 0);
            a1A = __builtin_amdgcn_mfma_f32_16x16x32_bf16(w1h[k], ch[k], a1A, 0, 0, 0);
            a1B = __builtin_amdgcn_mfma_f32_16x16x32_bf16(w1h[k], cl[k], a1B, 0, 0, 0);
            a1C = __builtin_amdgcn_mfma_f32_16x16x32_bf16(w1l[k], ch[k], a1C, 0, 0, 0);
        }
        p = 0.f;
#pragma unroll
        for (int r = 0; r < 4; ++r) {
            const float h = fast_tanh(a1A[r] + a1B[r] + a1C[r] + bias_r(bv1, r));
            p += h * bias_r(wfcv, r);
        }
    }

    // ---- FC reduce: out[b0+n] = sum over 64 hidden rows ----
    p += __shfl_xor(p, 16, 64);
    p += __shfl_xor(p, 32, 64);
    if (lane < 16) red[w][lane] = p;
    __syncthreads();
    if (w == 0 && lane < 16)
        out[b0 + lane] = red[0][lane] + red[1][lane] + red[2][lane] + red[3][lane] + b_fc[0];
}

extern "C" void kernel_launch(void* const* d_in, const int* in_sizes, int n_in,
                              void* d_out, int out_size, void* d_ws, size_t ws_size,
                              hipStream_t stream) {
    const float* x     = (const float*)d_in[0];
    const float* W_ih0 = (const float*)d_in[1];
    const float* W_hh0 = (const float*)d_in[2];
    const float* b_ih0 = (const float*)d_in[3];
    const float* b_hh0 = (const float*)d_in[4];
    const float* W_ih1 = (const float*)d_in[5];
    const float* W_hh1 = (const float*)d_in[6];
    const float* b_ih1 = (const float*)d_in[7];
    const float* b_hh1 = (const float*)d_in[8];
    const float* W_fc  = (const float*)d_in[9];
    const float* b_fc  = (const float*)d_in[10];
    float* out = (float*)d_out;

    rnn2_mfma<<<128, 256, 0, stream>>>(x, W_ih0, W_hh0, b_ih0, b_hh0,
                                       W_ih1, W_hh1, b_ih1, b_hh1,
                                       W_fc, b_fc, out);
}

// Round 4
// 396.677 us; speedup vs baseline: 2.1590x; 1.0966x over previous
//
#include <hip/hip_runtime.h>

#define TT 512

typedef __attribute__((ext_vector_type(8))) short short8;
typedef __attribute__((ext_vector_type(4))) float floatx4;

__device__ __forceinline__ unsigned short f2bf(float f) {  // RTNE (weights only)
    unsigned u = __float_as_uint(f);
    return (unsigned short)((u + 0x7FFFu + ((u >> 16) & 1u)) >> 16);
}
__device__ __forceinline__ float bf2f(unsigned short b) {
    return __uint_as_float(((unsigned)b) << 16);
}
// tanh(z) = 1 - 2/(exp(2z)+1); endpoints exact without clamp (e->inf => 1, e->0 => -1)
__device__ __forceinline__ float fast_tanh(float z) {
    const float e = __expf(2.f * z);
    return 1.f - __fdividef(2.f, e + 1.f);
}
__device__ __forceinline__ float f4e(const float4& v, int r) {
    return (r == 0) ? v.x : (r == 1) ? v.y : (r == 2) ? v.z : v.w;
}

// Layer-pipelined MFMA RNN, one barrier per superstep.
// Superstep s: h0(s)   = tanh(W0·h0(s-1) + x(s)·Wih0 + b0)
//              h1(s-1) = tanh(Wi1·h0(s-1) + W1·h1(s-2) + b1)
// h planes in LDS, chunked layout [chunk][batch][8] (conflict-free b128 reads).
// Split-3 bf16 (Whi*hhi + Whi*hlo + Wlo*hhi) ~ fp32; h split by TRUNCATION
// (hi = bits&0xffff0000, lo = h-hi, lo truncated by v_perm pack) — err <= 2^-16.
__global__ void __launch_bounds__(256, 1)
rnn2_mfma(const float* __restrict__ x,
          const float* __restrict__ W_ih0, const float* __restrict__ W_hh0,
          const float* __restrict__ b_ih0, const float* __restrict__ b_hh0,
          const float* __restrict__ W_ih1, const float* __restrict__ W_hh1,
          const float* __restrict__ b_ih1, const float* __restrict__ b_hh1,
          const float* __restrict__ W_fc, const float* __restrict__ b_fc,
          float* __restrict__ out)
{
    __shared__ short h0p[2][2][1024];  // [buf][part hi/lo][chunk*512 + 128q + 8n]
    __shared__ short h1p[2][2][1024];
    __shared__ float red[4][16];

    const int tid = threadIdx.x;
    const int lane = tid & 63;
    const int w = tid >> 6;
    const int n = lane & 15;
    const int q = lane >> 4;
    const int b0 = blockIdx.x * 16;

    // zero only h1 buf1 (= h1(-1)); all other planes are written before first read
    for (int i = tid; i < 1024; i += 256) ((float*)h1p[1])[i] = 0.f;

    // ---- static weight fragments (A-operand), rows [16w,16w+16) ----
    const int mrow = 16 * w + n;
    const int m4 = 16 * w + 4 * q;
    short8 w0h[2], w0l[2], wi1h[2], wi1l[2], w1h[2], w1l[2];
    auto mkfrag = [&](const float* p, short8& hi, short8& lo) {
#pragma unroll
        for (int j = 0; j < 8; ++j) {
            const float v = p[j];
            const unsigned short h = f2bf(v);
            hi[j] = (short)h;
            lo[j] = (short)f2bf(v - bf2f(h));
        }
    };
#pragma unroll
    for (int k = 0; k < 2; ++k) {
        mkfrag(W_hh0 + mrow * 64 + 32 * k + 8 * q, w0h[k], w0l[k]);
        mkfrag(W_ih1 + mrow * 64 + 32 * k + 8 * q, wi1h[k], wi1l[k]);
        mkfrag(W_hh1 + mrow * 64 + 32 * k + 8 * q, w1h[k], w1l[k]);
    }
    const float4 wih0v = *(const float4*)(W_ih0 + m4);
    float4 bv0 = *(const float4*)(b_ih0 + m4);
    { float4 t = *(const float4*)(b_hh0 + m4); bv0.x += t.x; bv0.y += t.y; bv0.z += t.z; bv0.w += t.w; }
    float4 bv1 = *(const float4*)(b_ih1 + m4);
    { float4 t = *(const float4*)(b_hh1 + m4); bv1.x += t.x; bv1.y += t.y; bv1.z += t.z; bv1.w += t.w; }
    const float4 wfcv = *(const float4*)(W_fc + m4);

    const int rbase = 128 * q + 8 * n;
    const int wbase = (2 * w + (q >> 1)) * 128 + 8 * n + 4 * (q & 1);

    // x stream: per-lane sequential through a 2KB row -> L1-resident; 1-step prefetch
    const float* xp = x + (long)(b0 + n) * TT;
    float xv = xp[0];
    float xn = xp[1];

    const floatx4 zero4 = {0.f, 0.f, 0.f, 0.f};

    // ---- pre-step s=0: h0(0) = tanh(x(0)*Wih0 + b0) -> buf 0 ----
    {
        unsigned tb[4]; float lo[4];
#pragma unroll
        for (int r = 0; r < 4; ++r) {
            const float h = fast_tanh(__builtin_fmaf(xv, f4e(wih0v, r), f4e(bv0, r)));
            tb[r] = __float_as_uint(h) & 0xffff0000u;
            lo[r] = h - __uint_as_float(tb[r]);
        }
        uint2 hh, hl;
        hh.x = __builtin_amdgcn_perm(tb[1], tb[0], 0x07060302u);
        hh.y = __builtin_amdgcn_perm(tb[3], tb[2], 0x07060302u);
        hl.x = __builtin_amdgcn_perm(__float_as_uint(lo[1]), __float_as_uint(lo[0]), 0x07060302u);
        hl.y = __builtin_amdgcn_perm(__float_as_uint(lo[3]), __float_as_uint(lo[2]), 0x07060302u);
        *(uint2*)&h0p[0][0][wbase] = hh;
        *(uint2*)&h0p[0][1][wbase] = hl;
    }
    __syncthreads();

    // ---- main loop: supersteps s = 1..511 ----
    for (int s = 1; s < TT; ++s) {
        xv = xn;
        xn = xp[(s + 1) & (TT - 1)];  // prefetch next step (wraps harmlessly at 511)

        const int rb0 = (s - 1) & 1, wb0 = s & 1;
        const int rb1 = s & 1,       wb1 = (s - 1) & 1;

        short8 bh[2], bl[2], ch[2], cl[2];
#pragma unroll
        for (int k = 0; k < 2; ++k) {
            bh[k] = *(const short8*)&h0p[rb0][0][rbase + 512 * k];
            bl[k] = *(const short8*)&h0p[rb0][1][rbase + 512 * k];
            ch[k] = *(const short8*)&h1p[rb1][0][rbase + 512 * k];
            cl[k] = *(const short8*)&h1p[rb1][1][rbase + 512 * k];
        }

        // seed bias (+ x*Wih0) into accumulator C-inputs
        floatx4 a0A = {__builtin_fmaf(xv, wih0v.x, bv0.x), __builtin_fmaf(xv, wih0v.y, bv0.y),
                       __builtin_fmaf(xv, wih0v.z, bv0.z), __builtin_fmaf(xv, wih0v.w, bv0.w)};
        floatx4 a1A = {bv1.x, bv1.y, bv1.z, bv1.w};
        floatx4 a0B = zero4, a0C = zero4, a1B = zero4, a1C = zero4;

#pragma unroll
        for (int k = 0; k < 2; ++k) {
            a0A = __builtin_amdgcn_mfma_f32_16x16x32_bf16(w0h[k],  bh[k], a0A, 0, 0, 0);
            a1A = __builtin_amdgcn_mfma_f32_16x16x32_bf16(wi1h[k], bh[k], a1A, 0, 0, 0);
            a0B = __builtin_amdgcn_mfma_f32_16x16x32_bf16(w0h[k],  bl[k], a0B, 0, 0, 0);
            a1B = __builtin_amdgcn_mfma_f32_16x16x32_bf16(wi1h[k], bl[k], a1B, 0, 0, 0);
            a0C = __builtin_amdgcn_mfma_f32_16x16x32_bf16(w0l[k],  bh[k], a0C, 0, 0, 0);
            a1C = __builtin_amdgcn_mfma_f32_16x16x32_bf16(wi1l[k], bh[k], a1C, 0, 0, 0);
            a1A = __builtin_amdgcn_mfma_f32_16x16x32_bf16(w1h[k],  ch[k], a1A, 0, 0, 0);
            a1B = __builtin_amdgcn_mfma_f32_16x16x32_bf16(w1h[k],  cl[k], a1B, 0, 0, 0);
            a1C = __builtin_amdgcn_mfma_f32_16x16x32_bf16(w1l[k],  ch[k], a1C, 0, 0, 0);
        }

        // ---- layer-0 epilogue: tanh + truncation split, write first ----
        {
            unsigned tb[4]; float lo[4];
#pragma unroll
            for (int r = 0; r < 4; ++r) {
                const float h = fast_tanh((a0A[r] + a0B[r]) + a0C[r]);
                tb[r] = __float_as_uint(h) & 0xffff0000u;
                lo[r] = h - __uint_as_float(tb[r]);
            }
            uint2 hh, hl;
            hh.x = __builtin_amdgcn_perm(tb[1], tb[0], 0x07060302u);
            hh.y = __builtin_amdgcn_perm(tb[3], tb[2], 0x07060302u);
            hl.x = __builtin_amdgcn_perm(__float_as_uint(lo[1]), __float_as_uint(lo[0]), 0x07060302u);
            hl.y = __builtin_amdgcn_perm(__float_as_uint(lo[3]), __float_as_uint(lo[2]), 0x07060302u);
            *(uint2*)&h0p[wb0][0][wbase] = hh;
            *(uint2*)&h0p[wb0][1][wbase] = hl;
        }
        // ---- layer-1 epilogue ----
        {
            unsigned tb[4]; float lo[4];
#pragma unroll
            for (int r = 0; r < 4; ++r) {
                const float h = fast_tanh((a1A[r] + a1B[r]) + a1C[r]);
                tb[r] = __float_as_uint(h) & 0xffff0000u;
                lo[r] = h - __uint_as_float(tb[r]);
            }
            uint2 hh, hl;
            hh.x = __builtin_amdgcn_perm(tb[1], tb[0], 0x07060302u);
            hh.y = __builtin_amdgcn_perm(tb[3], tb[2], 0x07060302u);
            hl.x = __builtin_amdgcn_perm(__float_as_uint(lo[1]), __float_as_uint(lo[0]), 0x07060302u);
            hl.y = __builtin_amdgcn_perm(__float_as_uint(lo[3]), __float_as_uint(lo[2]), 0x07060302u);
            *(uint2*)&h1p[wb1][0][wbase] = hh;
            *(uint2*)&h1p[wb1][1][wbase] = hl;
        }
        __syncthreads();
    }

    // ---- post-step: h1(511) = tanh(Wi1·h0(511) + W1·h1(510) + b1) + FC dot ----
    float p;
    {
        short8 bh[2], bl[2], ch[2], cl[2];
#pragma unroll
        for (int k = 0; k < 2; ++k) {
            bh[k] = *(const short8*)&h0p[1][0][rbase + 512 * k];  // h0(511): buf 511&1=1
            bl[k] = *(const short8*)&h0p[1][1][rbase + 512 * k];
            ch[k] = *(const short8*)&h1p[0][0][rbase + 512 * k];  // h1(510): buf 510&1=0
            cl[k] = *(const short8*)&h1p[0][1][rbase + 512 * k];
        }
        floatx4 a1A = {bv1.x, bv1.y, bv1.z, bv1.w};
        floatx4 a1B = zero4, a1C = zero4;
#pragma unroll
        for (int k = 0; k < 2; ++k) {
            a1A = __builtin_amdgcn_mfma_f32_16x16x32_bf16(wi1h[k], bh[k], a1A, 0, 0, 0);
            a1B = __builtin_amdgcn_mfma_f32_16x16x32_bf16(wi1h[k], bl[k], a1B, 0, 0, 0);
            a1C = __builtin_amdgcn_mfma_f32_16x16x32_bf16(wi1l[k], bh[k], a1C, 0, 0, 0);
            a1A = __builtin_amdgcn_mfma_f32_16x16x32_bf16(w1h[k],  ch[k], a1A, 0, 0, 0);
            a1B = __builtin_amdgcn_mfma_f32_16x16x32_bf16(w1h[k],  cl[k], a1B, 0, 0, 0);
            a1C = __builtin_amdgcn_mfma_f32_16x16x32_bf16(w1l[k],  ch[k], a1C, 0, 0, 0);
        }
        p = 0.f;
#pragma unroll
        for (int r = 0; r < 4; ++r) {
            const float h = fast_tanh((a1A[r] + a1B[r]) + a1C[r]);
            p = __builtin_fmaf(h, f4e(wfcv, r), p);
        }
    }

    // ---- FC reduce across the 64 hidden rows ----
    p += __shfl_xor(p, 16, 64);
    p += __shfl_xor(p, 32, 64);
    if (lane < 16) red[w][lane] = p;
    __syncthreads();
    if (w == 0 && lane < 16)
        out[b0 + lane] = red[0][lane] + red[1][lane] + red[2][lane] + red[3][lane] + b_fc[0];
}

extern "C" void kernel_launch(void* const* d_in, const int* in_sizes, int n_in,
                              void* d_out, int out_size, void* d_ws, size_t ws_size,
                              hipStream_t stream) {
    const float* x     = (const float*)d_in[0];
    const float* W_ih0 = (const float*)d_in[1];
    const float* W_hh0 = (const float*)d_in[2];
    const float* b_ih0 = (const float*)d_in[3];
    const float* b_hh0 = (const float*)d_in[4];
    const float* W_ih1 = (const float*)d_in[5];
    const float* W_hh1 = (const float*)d_in[6];
    const float* b_ih1 = (const float*)d_in[7];
    const float* b_hh1 = (const float*)d_in[8];
    const float* W_fc  = (const float*)d_in[9];
    const float* b_fc  = (const float*)d_in[10];
    float* out = (float*)d_out;

    rnn2_mfma<<<128, 256, 0, stream>>>(x, W_ih0, W_hh0, b_ih0, b_hh0,
                                       W_ih1, W_hh1, b_ih1, b_hh1,
                                       W_fc, b_fc, out);
}